// Round 1
// baseline (138.275 us; speedup 1.0000x reference)
//
#include <hip/hip_runtime.h>
#include <math.h>

#define NPTS 2048
#define NCLS 8
#define CONF 0.5f
#define DTHR 20.0f
#define TOPK 4
#define NTHREADS 256

// One block per (batch, class) pair. Steps:
//  1) softmax score for class c per point -> 64-bit sortable key in LDS
//  2) bitonic sort 2048 keys descending (stable via ~index tiebreak)
//  3) thread 0: greedy NMS walk (only needs kept-list <= 4; early exit at s<=0.5)
//  4) write this (b,c)'s 4 score slots, 8 point slots, 4 valid slots (zeros if invalid)
__global__ __launch_bounds__(NTHREADS) void decode_kernel(
    const float* __restrict__ loc,   // [B, N, 2]
    const float* __restrict__ cls,   // [B, N, C]
    float* __restrict__ out)         // [64 scores | 128 points | 64 valid]
{
    __shared__ unsigned long long keys[NPTS];
    __shared__ float px[NPTS];
    __shared__ float py[NPTS];

    const int b = blockIdx.x / NCLS;
    const int c = blockIdx.x % NCLS;
    const int tid = threadIdx.x;

    // ---- 1) scores + keys ----
    for (int n = tid; n < NPTS; n += NTHREADS) {
        const float* lg = cls + (size_t)(b * NPTS + n) * NCLS;
        float4 a0 = *(const float4*)(lg);
        float4 a1 = *(const float4*)(lg + 4);
        float v[8] = {a0.x, a0.y, a0.z, a0.w, a1.x, a1.y, a1.z, a1.w};
        float m = v[0];
        #pragma unroll
        for (int i = 1; i < 8; ++i) m = fmaxf(m, v[i]);
        float ssum = 0.f;
        float ec = 0.f;
        #pragma unroll
        for (int i = 0; i < 8; ++i) {
            float e = expf(v[i] - m);
            ssum += e;
            if (i == c) ec = e;
        }
        float s = ec / ssum;                      // softmax score for class c
        unsigned int sb = __float_as_uint(s);     // s in (0,1] -> bits monotonic
        keys[n] = ((unsigned long long)sb << 32) | (unsigned int)(~n);
        float2 p = *(const float2*)(loc + (size_t)(b * NPTS + n) * 2);
        px[n] = p.x;
        py[n] = p.y;
    }
    __syncthreads();

    // ---- 2) bitonic sort, descending ----
    for (int k = 2; k <= NPTS; k <<= 1) {
        for (int j = k >> 1; j > 0; j >>= 1) {
            for (int i = tid; i < NPTS; i += NTHREADS) {
                int ixj = i ^ j;
                if (ixj > i) {
                    unsigned long long a = keys[i];
                    unsigned long long bb = keys[ixj];
                    bool up = ((i & k) == 0);
                    // descending overall: "up" blocks keep larger first
                    if (up ? (a < bb) : (a > bb)) {
                        keys[i] = bb;
                        keys[ixj] = a;
                    }
                }
            }
            __syncthreads();
        }
    }

    // ---- 3) greedy NMS walk + 4) output ----
    if (tid == 0) {
        float ks0 = 0.f, ks1 = 0.f, ks2 = 0.f, ks3 = 0.f;
        float kx0 = 0.f, kx1 = 0.f, kx2 = 0.f, kx3 = 0.f;
        float ky0 = 0.f, ky1 = 0.f, ky2 = 0.f, ky3 = 0.f;
        int nk = 0;
        for (int i = 0; i < NPTS; ++i) {
            unsigned long long kk = keys[i];
            float s = __uint_as_float((unsigned int)(kk >> 32));
            if (!(s > CONF)) break;               // sorted: no more valid candidates
            int n = (int)(~(unsigned int)(kk & 0xFFFFFFFFull));
            float x = px[n];
            float y = py[n];
            bool sup = false;
            // check against kept list (matches reference: suppress when dist <= thr)
            if (nk > 0) {
                float dx = x - kx0, dy = y - ky0;
                if (sqrtf(__fmul_rn(dx, dx) + __fmul_rn(dy, dy)) <= DTHR) sup = true;
            }
            if (!sup && nk > 1) {
                float dx = x - kx1, dy = y - ky1;
                if (sqrtf(__fmul_rn(dx, dx) + __fmul_rn(dy, dy)) <= DTHR) sup = true;
            }
            if (!sup && nk > 2) {
                float dx = x - kx2, dy = y - ky2;
                if (sqrtf(__fmul_rn(dx, dx) + __fmul_rn(dy, dy)) <= DTHR) sup = true;
            }
            if (!sup) {
                if (nk == 0)      { ks0 = s; kx0 = x; ky0 = y; }
                else if (nk == 1) { ks1 = s; kx1 = x; ky1 = y; }
                else if (nk == 2) { ks2 = s; kx2 = x; ky2 = y; }
                else              { ks3 = s; kx3 = x; ky3 = y; }
                ++nk;
                if (nk == TOPK) break;
            }
        }

        const int base = b * NCLS + c;
        float* o_s = out + base * TOPK;           // [B,C,K] scores
        float* o_p = out + 64 + base * TOPK * 2;  // [B,C,K,2] points
        float* o_k = out + 192 + base * TOPK;     // [B,C,K] valid (0/1)

        o_s[0] = ks0; o_s[1] = ks1; o_s[2] = ks2; o_s[3] = ks3;
        o_p[0] = kx0; o_p[1] = ky0;
        o_p[2] = kx1; o_p[3] = ky1;
        o_p[4] = kx2; o_p[5] = ky2;
        o_p[6] = kx3; o_p[7] = ky3;
        o_k[0] = (nk > 0) ? 1.f : 0.f;
        o_k[1] = (nk > 1) ? 1.f : 0.f;
        o_k[2] = (nk > 2) ? 1.f : 0.f;
        o_k[3] = (nk > 3) ? 1.f : 0.f;
    }
}

extern "C" void kernel_launch(void* const* d_in, const int* in_sizes, int n_in,
                              void* d_out, int out_size, void* d_ws, size_t ws_size,
                              hipStream_t stream) {
    const float* loc = (const float*)d_in[0];  // locations [B,N,2]
    const float* cls = (const float*)d_in[1];  // classifications [B,N,C]
    float* out = (float*)d_out;
    decode_kernel<<<16, NTHREADS, 0, stream>>>(loc, cls, out);
}

// Round 2
// 61.242 us; speedup vs baseline: 2.2578x; 2.2578x over previous
//
#include <hip/hip_runtime.h>
#include <math.h>

#define NPTS 2048
#define NCLS 8
#define CONF 0.5f
#define DTHR 20.0f
#define TOPK 4
#define NT 256
#define EPT (NPTS / NT)   // 8 points per thread
#define NWAVES (NT / 64)  // 4

// One block per (batch, class). Greedy NMS == iterative max-selection:
//   kept[k] = argmax over still-unsuppressed valid keys; then suppress all
//   points within DTHR of it. Only TOPK=4 iterations needed, no sort.
// Key = (score_bits << 32) | ~n  -> max key == (higher score, then smaller
// original index), matching JAX's stable descending argsort exactly.
__global__ __launch_bounds__(NT) void decode_kernel(
    const float* __restrict__ loc,   // [B, N, 2]
    const float* __restrict__ cls,   // [B, N, C]
    float* __restrict__ out)         // [64 scores | 128 points | 64 valid]
{
    __shared__ float px[NPTS];
    __shared__ float py[NPTS];
    __shared__ unsigned long long wmax[NWAVES];

    const int b = blockIdx.x >> 3;
    const int c = blockIdx.x & 7;
    const int tid = threadIdx.x;
    const int lane = tid & 63;
    const int wid = tid >> 6;

    unsigned long long key[EPT];
    float mx[EPT], my[EPT];

    // ---- load + softmax score for class c; keys in registers ----
    #pragma unroll
    for (int e = 0; e < EPT; ++e) {
        const int n = tid + e * NT;
        const float* lg = cls + (size_t)(b * NPTS + n) * NCLS;
        float4 a0 = *(const float4*)(lg);
        float4 a1 = *(const float4*)(lg + 4);
        float v[8] = {a0.x, a0.y, a0.z, a0.w, a1.x, a1.y, a1.z, a1.w};
        float m = v[0];
        #pragma unroll
        for (int i = 1; i < 8; ++i) m = fmaxf(m, v[i]);
        float ssum = 0.f, ec = 0.f;
        #pragma unroll
        for (int i = 0; i < 8; ++i) {
            float e2 = expf(v[i] - m);
            ssum += e2;
            if (i == c) ec = e2;
        }
        float s = ec / ssum;
        float2 p = *(const float2*)(loc + (size_t)(b * NPTS + n) * 2);
        px[n] = p.x;
        py[n] = p.y;
        mx[e] = p.x;
        my[e] = p.y;
        key[e] = (s > CONF)
                     ? (((unsigned long long)__float_as_uint(s) << 32) |
                        (unsigned int)(~n))
                     : 0ull;
    }
    __syncthreads();

    float ks[TOPK] = {0.f, 0.f, 0.f, 0.f};
    float kx[TOPK] = {0.f, 0.f, 0.f, 0.f};
    float ky[TOPK] = {0.f, 0.f, 0.f, 0.f};
    int nk = 0;

    for (int it = 0; it < TOPK; ++it) {
        // ---- block-wide max key ----
        unsigned long long m = key[0];
        #pragma unroll
        for (int e = 1; e < EPT; ++e) m = (key[e] > m) ? key[e] : m;
        #pragma unroll
        for (int o = 32; o > 0; o >>= 1) {
            unsigned long long t = __shfl_xor(m, o, 64);
            m = (t > m) ? t : m;
        }
        if (lane == 0) wmax[wid] = m;
        __syncthreads();
        m = wmax[0];
        #pragma unroll
        for (int w = 1; w < NWAVES; ++w) m = (wmax[w] > m) ? wmax[w] : m;
        __syncthreads();   // all reads of wmax done before next iteration's write

        if (m == 0ull) break;   // no valid unsuppressed candidate left (uniform)

        const float s = __uint_as_float((unsigned int)(m >> 32));
        const int n = (int)(~(unsigned int)(m & 0xFFFFFFFFull));
        const float sx = px[n];   // LDS broadcast (same address all lanes)
        const float sy = py[n];

        ks[nk] = s; kx[nk] = sx; ky[nk] = sy;
        ++nk;

        // ---- suppress everything within DTHR of the selected point ----
        #pragma unroll
        for (int e = 0; e < EPT; ++e) {
            float dx = mx[e] - sx;
            float dy = my[e] - sy;
            if (sqrtf(__fmul_rn(dx, dx) + __fmul_rn(dy, dy)) <= DTHR)
                key[e] = 0ull;   // also zeroes the selected point itself (d=0)
        }
    }

    // ---- outputs (zeros for invalid slots; d_out is poisoned each launch) ----
    if (tid == 0) {
        const int base = b * NCLS + c;
        float* o_s = out + base * TOPK;            // [B,C,K] scores
        float* o_p = out + 64 + base * TOPK * 2;   // [B,C,K,2] points
        float* o_k = out + 192 + base * TOPK;      // [B,C,K] valid

        #pragma unroll
        for (int k = 0; k < TOPK; ++k) {
            o_s[k] = ks[k];
            o_p[2 * k] = kx[k];
            o_p[2 * k + 1] = ky[k];
            o_k[k] = (nk > k) ? 1.f : 0.f;
        }
    }
}

extern "C" void kernel_launch(void* const* d_in, const int* in_sizes, int n_in,
                              void* d_out, int out_size, void* d_ws, size_t ws_size,
                              hipStream_t stream) {
    const float* loc = (const float*)d_in[0];  // locations [B,N,2]
    const float* cls = (const float*)d_in[1];  // classifications [B,N,C]
    float* out = (float*)d_out;
    decode_kernel<<<16, NT, 0, stream>>>(loc, cls, out);
}